// Round 2
// baseline (1020.609 us; speedup 1.0000x reference)
//
#include <hip/hip_runtime.h>
#include <hip/hip_cooperative_groups.h>
#include <math.h>

namespace cg = cooperative_groups;

#define NN 1024
#define NJ 960          // N - I: the "reg" region (global indices 64..1023)
#define NWARM 25

// ws layout, in floats:
//   S2c[j][m]: (d/N)*S[64+m][64+j]; m<64 (masked rows) stored as 0.
//   Wt[j][k] : (d/N)*S[k][64+j]   (head weights, k in [0,64))
//   hd[j]    : (1/N)*sum_k Wt[j][k]  (constant head contribution in warmup)
//   base[j]  : batch-step constant = (y25[j] + y25.S2col_j)/s25
//   ybuf[2][960] : ping-pong unnormalized warmup state
//   part[2][240] : per-block partial sums s_{t+1} (parity t&1)
#define OFF_S2   0u
#define OFF_WT   (960u * 960u)
#define OFF_HD   (OFF_WT + 960u * 64u)
#define OFF_BASE (OFF_HD + 960u)
#define OFF_YB   (OFF_BASE + 960u)
#define OFF_PART (OFF_YB + 2u * 960u)     // end ~987,360 floats (~3.95 MB)

// One cooperative launch: prep (S2/Wt/hd/y0) -> 25 warmup iterations with
// grid.sync between -> final base[] computation.
// Block b owns columns j in [4b, 4b+4); 64 lanes per column.
__global__ __launch_bounds__(256) void coop_k(const float* __restrict__ ident,
                                              const float* __restrict__ enh,
                                              const float* __restrict__ inh,
                                              const float* __restrict__ beta,
                                              const float* __restrict__ delta,
                                              float* __restrict__ ws) {
  cg::grid_group grid = cg::this_grid();
  const int tid = threadIdx.x;
  const int grp = tid >> 6;
  const int l = tid & 63;
  const int j = blockIdx.x * 4 + grp;

  // ---- phase 0: prep ----
  {
    const float b = beta[0];
    const float dN = delta[0] / (float)NN;
    const float cj = ident[64 + j];
    #pragma unroll
    for (int i = 0; i < 15; ++i) {
      int m = l + i * 64;
      float v = 0.0f;
      if (m >= 64) {
        int g = 64 + m;
        v = dN * (expf(-b * fabsf(enh[g] - cj)) - expf(-b * fabsf(inh[g] - cj)));
      }
      ws[OFF_S2 + (size_t)j * NJ + m] = v;
    }
    float wv = dN * (expf(-b * fabsf(enh[l] - cj)) - expf(-b * fabsf(inh[l] - cj)));
    ws[OFF_WT + (size_t)j * 64 + l] = wv;
    float h = wv;
    #pragma unroll
    for (int off = 32; off >= 1; off >>= 1) h += __shfl_xor(h, off);
    if (l == 0) {
      ws[OFF_HD + j] = h / (float)NN;
      ws[OFF_YB + j] = 1.0f / (float)NN;   // y_0 (unnormalized, s_0 = 1)
    }
  }

  __shared__ float warp_s[4];
  __shared__ float gsum[4];

  for (int t = 0; t <= NWARM; ++t) {
    grid.sync();   // makes prior iteration's (or phase-0's) writes visible

    // s_t: redundant per-block sum of 240 partials from iteration t-1
    float s = 1.0f;
    if (t > 0) {
      float sp = 0.0f;
      if (tid < 240) sp = ws[OFF_PART + (size_t)((t - 1) & 1) * 240 + tid];
      #pragma unroll
      for (int off = 32; off >= 1; off >>= 1) sp += __shfl_xor(sp, off);
      if (l == 0) warp_s[grp] = sp;
      __syncthreads();
      s = warp_s[0] + warp_s[1] + warp_s[2] + warp_s[3];
    }

    const float* __restrict__ ycur = ws + OFF_YB + (size_t)(t & 1) * NJ;
    float* __restrict__ ynext = ws + OFF_YB + (size_t)((t + 1) & 1) * NJ;
    const float* __restrict__ S2row = ws + OFF_S2 + (size_t)j * NJ;

    float dot = 0.0f;
    #pragma unroll
    for (int i = 0; i < 15; ++i) {
      int m = l + i * 64;
      dot = fmaf(ycur[m], S2row[m], dot);
    }
    #pragma unroll
    for (int off = 32; off >= 1; off >>= 1) dot += __shfl_xor(dot, off);

    if (l == 0) {
      float pre = ycur[j] + dot;
      pre = (s > 0.0f) ? pre / s : pre;   // conc_j + tail part of dc_j
      float contrib = 0.0f;
      if (t < NWARM) {
        float yv = fmaxf(pre + ws[OFF_HD + j], 0.0f);
        ynext[j] = yv;
        contrib = yv;
      } else {
        ws[OFF_BASE + j] = pre;           // head part comes from inputs later
      }
      gsum[grp] = contrib;
    }
    __syncthreads();
    if (t < NWARM && tid == 0)
      ws[OFF_PART + (size_t)(t & 1) * 240 + blockIdx.x] =
          gsum[0] + gsum[1] + gsum[2] + gsum[3];
  }
}

__device__ __forceinline__ float dot16(const float* __restrict__ a,
                                       const float4* __restrict__ w) {
  float4 w0 = w[0], w1 = w[1], w2 = w[2], w3 = w[3];
  float s0 = fmaf(a[3], w0.w, fmaf(a[2], w0.z, fmaf(a[1], w0.y, a[0] * w0.x)));
  float s1 = fmaf(a[7], w1.w, fmaf(a[6], w1.z, fmaf(a[5], w1.y, a[4] * w1.x)));
  float s2 = fmaf(a[11], w2.w, fmaf(a[10], w2.z, fmaf(a[9], w2.y, a[8] * w2.x)));
  float s3 = fmaf(a[15], w3.w, fmaf(a[14], w3.z, fmaf(a[13], w3.y, a[12] * w3.x)));
  return (s0 + s1) + (s2 + s3);
}

// Block = 256 threads = 8 rows x (4 k-lanes x 8 j-chunks).
// Lane (c,q) of a row: holds inputs k in [16c,16c+16), handles columns
// j in [120q, 120q+120). Per column: 16 FMA + 2 shfl (c-reduce). ssum is
// completed with a 3-shfl q-reduce. Row's 32 lanes sit in one wave.
__global__ __launch_bounds__(256) void batch_k(const float* __restrict__ inp,
                                               const float* __restrict__ ws,
                                               float* __restrict__ out) {
  const int tid = threadIdx.x;
  const int c = tid & 3;
  const int q = (tid >> 2) & 7;
  const int rl = tid >> 5;
  const int r = blockIdx.x * 8 + rl;
  const float* __restrict__ Wt = ws + OFF_WT;
  const float* __restrict__ base = ws + OFF_BASE;

  float a[16];
  {
    const float4* ip = (const float4*)(inp + (size_t)r * 64 + c * 16);
    float4 v0 = ip[0], v1 = ip[1], v2 = ip[2], v3 = ip[3];
    a[0] = v0.x; a[1] = v0.y; a[2] = v0.z; a[3] = v0.w;
    a[4] = v1.x; a[5] = v1.y; a[6] = v1.z; a[7] = v1.w;
    a[8] = v2.x; a[9] = v2.y; a[10] = v2.z; a[11] = v2.w;
    a[12] = v3.x; a[13] = v3.y; a[14] = v3.z; a[15] = v3.w;
  }

  float y[16];
  float ssum = 0.0f;
  const int j0 = q * 120;

  // jj < 64: for q==0 these are the output columns -> stash y (full unroll so
  // the y[] index is compile-time; lane c keeps jj in [16c,16c+16)).
  #pragma unroll
  for (int jj = 0; jj < 64; ++jj) {
    int j = j0 + jj;
    float d4 = dot16(a, (const float4*)(Wt + (size_t)j * 64 + c * 16));
    d4 += __shfl_xor(d4, 1);
    d4 += __shfl_xor(d4, 2);
    float yv = fmaxf(d4 + base[j], 0.0f);
    ssum += yv;
    if (q == 0 && (jj >> 4) == c) y[jj & 15] = yv;
  }
  #pragma unroll 8
  for (int jj = 64; jj < 120; ++jj) {
    int j = j0 + jj;
    float d4 = dot16(a, (const float4*)(Wt + (size_t)j * 64 + c * 16));
    d4 += __shfl_xor(d4, 1);
    d4 += __shfl_xor(d4, 2);
    ssum += fmaxf(d4 + base[j], 0.0f);
  }

  // complete ssum across the 8 j-chunks (lane bits 2..4)
  ssum += __shfl_xor(ssum, 4);
  ssum += __shfl_xor(ssum, 8);
  ssum += __shfl_xor(ssum, 16);

  if (q == 0) {
    float invs = (ssum > 0.0f) ? 1.0f / ssum : 1.0f;
    float4* op = (float4*)(out + (size_t)r * 64 + c * 16);
    float4 o;
    o.x = y[0] * invs;  o.y = y[1] * invs;  o.z = y[2] * invs;  o.w = y[3] * invs;  op[0] = o;
    o.x = y[4] * invs;  o.y = y[5] * invs;  o.z = y[6] * invs;  o.w = y[7] * invs;  op[1] = o;
    o.x = y[8] * invs;  o.y = y[9] * invs;  o.z = y[10] * invs; o.w = y[11] * invs; op[2] = o;
    o.x = y[12] * invs; o.y = y[13] * invs; o.z = y[14] * invs; o.w = y[15] * invs; op[3] = o;
  }
}

extern "C" void kernel_launch(void* const* d_in, const int* in_sizes, int n_in,
                              void* d_out, int out_size, void* d_ws, size_t ws_size,
                              hipStream_t stream) {
  const float* inp   = (const float*)d_in[0];
  const float* ident = (const float*)d_in[1];
  const float* enh   = (const float*)d_in[2];
  const float* inh   = (const float*)d_in[3];
  const float* beta  = (const float*)d_in[4];
  const float* delta = (const float*)d_in[5];
  float* ws  = (float*)d_ws;
  float* out = (float*)d_out;

  void* args[6] = {(void*)&ident, (void*)&enh, (void*)&inh,
                   (void*)&beta, (void*)&delta, (void*)&ws};
  hipLaunchCooperativeKernel(reinterpret_cast<void*>(coop_k),
                             dim3(240), dim3(256), args, 0, stream);
  hipLaunchKernelGGL(batch_k, dim3(2048), dim3(256), 0, stream, inp, ws, out);
}

// Round 3
// 274.256 us; speedup vs baseline: 3.7214x; 3.7214x over previous
//
#include <hip/hip_runtime.h>
#include <math.h>

#define NN 1024
#define NJ 960          // N - I: the "reg" region (global indices 64..1023)
#define NWARM 25

// ws layout, in floats:
//   S2c[j][m]: (d/N)*S[64+m][64+j]; m<64 (masked rows) stored as 0.
//   Wt[j][k] : (d/N)*S[k][64+j]   (head weights, k in [0,64))
//   hd[j]    : (1/N)*sum_k Wt[j][k]  (constant head contribution in warmup)
//   base[j]  : batch-step constant = (y25[j] + y25.S2col_j)/s25
//   ybuf[2][960] : ping-pong unnormalized warmup state
//   slots[32]    : s_t normalization sums (slot[0]=1)
#define OFF_S2   0u
#define OFF_WT   (960u * 960u)
#define OFF_HD   (OFF_WT + 960u * 64u)
#define OFF_BASE (OFF_HD + 960u)
#define OFF_YB   (OFF_BASE + 960u)
#define OFF_SLOT (OFF_YB + 2u * 960u)     // ~3.95 MB total

__global__ void prep_k(const float* __restrict__ ident,
                       const float* __restrict__ enh,
                       const float* __restrict__ inh,
                       const float* __restrict__ beta,
                       const float* __restrict__ delta,
                       float* __restrict__ ws) {
  const int j = blockIdx.x;            // 0..959 -> global column 64+j
  const float b = beta[0];
  const float dN = delta[0] / (float)NN;
  const float cj = ident[64 + j];

  for (int m = threadIdx.x; m < NJ; m += blockDim.x) {
    float v = 0.0f;
    if (m >= 64) {
      int g = 64 + m;
      v = dN * (expf(-b * fabsf(enh[g] - cj)) - expf(-b * fabsf(inh[g] - cj)));
    }
    ws[OFF_S2 + (size_t)j * NJ + m] = v;
  }
  if (threadIdx.x < 64) {
    int k = threadIdx.x;
    float wv = dN * (expf(-b * fabsf(enh[k] - cj)) - expf(-b * fabsf(inh[k] - cj)));
    ws[OFF_WT + (size_t)j * 64 + k] = wv;
    float h = wv;
    #pragma unroll
    for (int off = 32; off >= 1; off >>= 1) h += __shfl_xor(h, off);
    if (k == 0) {
      ws[OFF_HD + j] = h / (float)NN;
      ws[OFF_YB + j] = 1.0f / (float)NN;     // y_0 (unnormalized, s_0 = 1)
    }
  }
  // slot init (block 0 only)
  if (blockIdx.x == 0 && threadIdx.x < 32)
    ws[OFF_SLOT + threadIdx.x] = (threadIdx.x == 0) ? 1.0f : 0.0f;
}

// One warmup iteration t (or, FINAL: compute base[] from converged state).
template <bool FINAL>
__global__ void warm_k(float* __restrict__ ws, int t) {
  const int grp = threadIdx.x >> 6;
  const int l = threadIdx.x & 63;
  const int j = blockIdx.x * 4 + grp;
  const float* __restrict__ S2row = ws + OFF_S2 + (size_t)j * NJ;
  const float* __restrict__ ycur = ws + OFF_YB + (size_t)(t & 1) * NJ;
  float* __restrict__ ynext = ws + OFF_YB + (size_t)((t + 1) & 1) * NJ;

  float dot = 0.0f;
  #pragma unroll
  for (int i = 0; i < 15; ++i) {
    int m = l + i * 64;
    dot = fmaf(ycur[m], S2row[m], dot);
  }
  #pragma unroll
  for (int off = 32; off >= 1; off >>= 1) dot += __shfl_xor(dot, off);

  __shared__ float blocksum;
  if (threadIdx.x == 0) blocksum = 0.0f;
  __syncthreads();

  if (l == 0) {
    float s = ws[OFF_SLOT + t];
    float pre = ycur[j] + dot;
    pre = (s > 0.0f) ? pre / s : pre;
    if (!FINAL) {
      float yv = fmaxf(pre + ws[OFF_HD + j], 0.0f);
      ynext[j] = yv;
      atomicAdd(&blocksum, yv);
    } else {
      ws[OFF_BASE + j] = pre;
    }
  }
  __syncthreads();
  if (!FINAL && threadIdx.x == 0) atomicAdd(&ws[OFF_SLOT + t + 1], blocksum);
}

// Batch step: one ROW per LANE. Block = 1024 threads = 16 waves, all covering
// the same 64 rows (row = blockIdx*64 + lane, a[64] in VGPRs). Wave w handles
// columns [60w, 60w+60); within a wave every lane processes the SAME column j
// at the same time, so the W-row address is wave-uniform -> compiler emits
// s_load, and the 64 FMAs/column read W from SGPRs (zero per-lane W traffic).
__global__ __launch_bounds__(1024) void batch_k(const float* __restrict__ inp,
                                                const float* __restrict__ ws,
                                                float* __restrict__ out) {
  __shared__ float ybuf[64 * 65];   // [col j<64][row], stride 65 (bank-safe)
  __shared__ float ssbuf[16 * 64];  // [wave][row] partial sums
  __shared__ float invs[64];

  const int tid = threadIdx.x;
  const int lane = tid & 63;
  const int wid = __builtin_amdgcn_readfirstlane(tid >> 6);  // uniform wave id
  const int row = blockIdx.x * 64 + lane;

  float a[64];
  {
    const float4* ip = (const float4*)(inp + (size_t)row * 64);
    #pragma unroll
    for (int v = 0; v < 16; ++v) {
      float4 t4 = ip[v];
      a[4 * v + 0] = t4.x; a[4 * v + 1] = t4.y;
      a[4 * v + 2] = t4.z; a[4 * v + 3] = t4.w;
    }
  }

  const float* __restrict__ Wt = ws + OFF_WT;
  const float* __restrict__ base = ws + OFF_BASE;
  const int j0 = wid * 60;

  float ssum = 0.0f;
  for (int i = 0; i < 60; ++i) {
    const int j = j0 + i;                              // wave-uniform
    const float* __restrict__ wrow = Wt + (size_t)j * 64;  // uniform -> s_load
    float d0 = 0.0f, d1 = 0.0f, d2 = 0.0f, d3 = 0.0f;
    #pragma unroll
    for (int k = 0; k < 16; ++k) {
      d0 = fmaf(a[4 * k + 0], wrow[4 * k + 0], d0);
      d1 = fmaf(a[4 * k + 1], wrow[4 * k + 1], d1);
      d2 = fmaf(a[4 * k + 2], wrow[4 * k + 2], d2);
      d3 = fmaf(a[4 * k + 3], wrow[4 * k + 3], d3);
    }
    float yv = fmaxf(((d0 + d1) + (d2 + d3)) + base[j], 0.0f);
    ssum += yv;
    if (j < 64) ybuf[j * 65 + lane] = yv;              // uniform branch
  }
  ssbuf[wid * 64 + lane] = ssum;
  __syncthreads();

  if (wid == 0) {
    float t = 0.0f;
    #pragma unroll
    for (int w = 0; w < 16; ++w) t += ssbuf[w * 64 + lane];
    invs[lane] = (t > 0.0f) ? 1.0f / t : 1.0f;
  }
  __syncthreads();

  // epilogue: 64 rows x 16 float4 = 1024 float4 -> one per thread, coalesced
  {
    const int lr = tid >> 4;          // local row
    const int c4 = tid & 15;          // float4 within row
    const float s = invs[lr];
    float4 o;
    o.x = ybuf[(4 * c4 + 0) * 65 + lr] * s;
    o.y = ybuf[(4 * c4 + 1) * 65 + lr] * s;
    o.z = ybuf[(4 * c4 + 2) * 65 + lr] * s;
    o.w = ybuf[(4 * c4 + 3) * 65 + lr] * s;
    ((float4*)out)[(size_t)blockIdx.x * 1024 + tid] = o;
  }
}

extern "C" void kernel_launch(void* const* d_in, const int* in_sizes, int n_in,
                              void* d_out, int out_size, void* d_ws, size_t ws_size,
                              hipStream_t stream) {
  const float* inp   = (const float*)d_in[0];
  const float* ident = (const float*)d_in[1];
  const float* enh   = (const float*)d_in[2];
  const float* inh   = (const float*)d_in[3];
  const float* beta  = (const float*)d_in[4];
  const float* delta = (const float*)d_in[5];
  float* ws  = (float*)d_ws;
  float* out = (float*)d_out;

  hipLaunchKernelGGL(prep_k, dim3(960), dim3(256), 0, stream,
                     ident, enh, inh, beta, delta, ws);
  for (int t = 0; t < NWARM; ++t)
    hipLaunchKernelGGL((warm_k<false>), dim3(240), dim3(256), 0, stream, ws, t);
  hipLaunchKernelGGL((warm_k<true>), dim3(240), dim3(256), 0, stream, ws, NWARM);
  hipLaunchKernelGGL(batch_k, dim3(256), dim3(1024), 0, stream, inp, ws, out);
}

// Round 4
// 209.222 us; speedup vs baseline: 4.8781x; 1.3108x over previous
//
#include <hip/hip_runtime.h>
#include <math.h>

#define NJ 960           // N - I: the "reg" region (global indices 64..1023)
#define NWARM 25
#define NBLK 64          // blocks in the persistent front kernel
#define NC 15            // columns owned per block (64*15 = 960)

typedef unsigned long long u64;
typedef unsigned int u32;

// ws layout (bytes):
//   Y[2][960] u64 : epoch-tagged y values (tag = iter+1, fp32 bits low)  @ 0
//   P[2][64]  u64 : epoch-tagged per-block partial sums                  @ 15360
//   Wt[960][64] f32 : (d/N)*S[k][64+j] head weights                      @ 16384
//   base[960]  f32 : batch-step constant                                 @ 262144
#define WT_F   4096u
#define BASE_F (WT_F + 960u * 64u)

__device__ __forceinline__ u64 pack_tv(u32 tag, float v) {
  return ((u64)tag << 32) | (u64)__float_as_uint(v);
}
__device__ __forceinline__ void ast(u64* p, u64 v) {
  __hip_atomic_store(p, v, __ATOMIC_RELAXED, __HIP_MEMORY_SCOPE_AGENT);
}
__device__ __forceinline__ u64 ald(const u64* p) {
  return __hip_atomic_load(p, __ATOMIC_RELAXED, __HIP_MEMORY_SCOPE_AGENT);
}

// Persistent front kernel: computes Wt, per-block hd + S2 slice (LDS), then
// runs all 25 warmup iterations + final base[] with fence-free epoch-tagged
// dataflow sync. 64 blocks co-resident trivially (256 CUs).
__global__ __launch_bounds__(1024) void front_k(const float* __restrict__ ident,
                                                const float* __restrict__ enh,
                                                const float* __restrict__ inh,
                                                const float* __restrict__ beta,
                                                const float* __restrict__ delta,
                                                void* __restrict__ wsv) {
  u64* Y = (u64*)wsv;
  u64* P = Y + 2 * NJ;
  float* wsf = (float*)wsv;
  float* Wt = wsf + WT_F;
  float* base = wsf + BASE_F;

  __shared__ float S2loc[NC * NJ];   // [col_local][src m], 57.6 KB
  __shared__ float yloc[NJ];
  __shared__ float pvals[NBLK];
  __shared__ float psums[NC];
  __shared__ float hdl[NC];

  const int tid = threadIdx.x;
  const int wid = tid >> 6, lane = tid & 63;
  const int b = blockIdx.x;
  const int j0 = b * NC;
  const float bc = beta[0];
  const float dN = delta[0] / 1024.0f;

  // --- A1: Wt rows + head constant hd for this block's columns ---
  if (wid < NC) {
    int j = j0 + wid;
    float cj = ident[64 + j];
    float wv = dN * (expf(-bc * fabsf(enh[lane] - cj)) -
                     expf(-bc * fabsf(inh[lane] - cj)));
    Wt[j * 64 + lane] = wv;
    float h = wv;
    #pragma unroll
    for (int off = 32; off >= 1; off >>= 1) h += __shfl_xor(h, off);
    if (lane == 0) hdl[wid] = h * (1.0f / 1024.0f);
  }
  // --- A2: S2 slice into LDS (sources m<64 are the masked rows -> 0) ---
  for (int idx = tid; idx < NC * NJ; idx += 1024) {
    int c = idx / NJ, m = idx - c * NJ;
    float v = 0.0f;
    if (m >= 64) {
      float cj = ident[64 + j0 + c];
      int g = 64 + m;
      v = dN * (expf(-bc * fabsf(enh[g] - cj)) - expf(-bc * fabsf(inh[g] - cj)));
    }
    S2loc[idx] = v;
  }
  // --- A3: publish y_0 = 1/1024 (slot 0, tag 1) for owned columns ---
  if (tid < NC) ast(&Y[j0 + tid], pack_tv(1u, 1.0f / 1024.0f));
  __syncthreads();

  for (int t = 0; t <= NWARM; ++t) {
    // 1: gather y_t (tag t+1) and, for t>0, partials of s_t
    if (tid < NJ) {
      u64* src = &Y[(size_t)(t & 1) * NJ + tid];
      u64 v = ald(src);
      while ((u32)(v >> 32) != (u32)(t + 1)) {
        __builtin_amdgcn_s_sleep(1);
        v = ald(src);
      }
      yloc[tid] = __uint_as_float((u32)v);
    }
    if (t > 0 && tid < NBLK) {
      u64* src = &P[(size_t)(t & 1) * NBLK + tid];
      u64 v = ald(src);
      while ((u32)(v >> 32) != (u32)(t + 1)) {
        __builtin_amdgcn_s_sleep(1);
        v = ald(src);
      }
      pvals[tid] = __uint_as_float((u32)v);
    }
    __syncthreads();

    // 2: s_t (redundant per-thread sum of 64 LDS broadcasts)
    float s = 1.0f;
    if (t > 0) {
      float acc = 0.0f;
      #pragma unroll
      for (int i = 0; i < NBLK; ++i) acc += pvals[i];
      s = acc;
    }

    // 3: one column per wave: dot(y_t, S2col) + update
    if (wid < NC) {
      const float* __restrict__ row = &S2loc[wid * NJ];
      float d = 0.0f;
      #pragma unroll
      for (int i = 0; i < 15; ++i)
        d = fmaf(yloc[lane + 64 * i], row[lane + 64 * i], d);
      #pragma unroll
      for (int off = 32; off >= 1; off >>= 1) d += __shfl_xor(d, off);
      if (lane == 0) {
        float pre = yloc[j0 + wid] + d;
        pre = (s > 0.0f) ? pre / s : pre;
        if (t < NWARM) {
          float yv = fmaxf(pre + hdl[wid], 0.0f);
          psums[wid] = yv;
          ast(&Y[(size_t)((t + 1) & 1) * NJ + j0 + wid],
              pack_tv((u32)(t + 2), yv));
        } else {
          base[j0 + wid] = pre;   // normal store; kernel-end flush covers it
        }
      }
    }
    __syncthreads();

    // 4: publish this block's partial of s_{t+1} (tag t+2)
    if (t < NWARM && tid < NBLK) {   // wave 0 entirely
      float pv = (tid < NC) ? psums[tid] : 0.0f;
      #pragma unroll
      for (int off = 32; off >= 1; off >>= 1) pv += __shfl_xor(pv, off);
      if (tid == 0)
        ast(&P[(size_t)((t + 1) & 1) * NBLK + b], pack_tv((u32)(t + 2), pv));
    }
  }
}

// Batch step (unchanged from round 3, 67 us): one ROW per LANE; 16 waves all
// covering the same 64 rows; wave-uniform W row address -> s_load into SGPRs,
// zero per-lane W traffic.
__global__ __launch_bounds__(1024) void batch_k(const float* __restrict__ inp,
                                                const float* __restrict__ ws,
                                                float* __restrict__ out) {
  __shared__ float ybuf[64 * 65];
  __shared__ float ssbuf[16 * 64];
  __shared__ float invs[64];

  const int tid = threadIdx.x;
  const int lane = tid & 63;
  const int wid = __builtin_amdgcn_readfirstlane(tid >> 6);
  const int row = blockIdx.x * 64 + lane;

  float a[64];
  {
    const float4* ip = (const float4*)(inp + (size_t)row * 64);
    #pragma unroll
    for (int v = 0; v < 16; ++v) {
      float4 t4 = ip[v];
      a[4 * v + 0] = t4.x; a[4 * v + 1] = t4.y;
      a[4 * v + 2] = t4.z; a[4 * v + 3] = t4.w;
    }
  }

  const float* __restrict__ Wt = ws + WT_F;
  const float* __restrict__ base = ws + BASE_F;
  const int j0 = wid * 60;

  float ssum = 0.0f;
  for (int i = 0; i < 60; ++i) {
    const int j = j0 + i;
    const float* __restrict__ wrow = Wt + (size_t)j * 64;
    float d0 = 0.0f, d1 = 0.0f, d2 = 0.0f, d3 = 0.0f;
    #pragma unroll
    for (int k = 0; k < 16; ++k) {
      d0 = fmaf(a[4 * k + 0], wrow[4 * k + 0], d0);
      d1 = fmaf(a[4 * k + 1], wrow[4 * k + 1], d1);
      d2 = fmaf(a[4 * k + 2], wrow[4 * k + 2], d2);
      d3 = fmaf(a[4 * k + 3], wrow[4 * k + 3], d3);
    }
    float yv = fmaxf(((d0 + d1) + (d2 + d3)) + base[j], 0.0f);
    ssum += yv;
    if (j < 64) ybuf[j * 65 + lane] = yv;
  }
  ssbuf[wid * 64 + lane] = ssum;
  __syncthreads();

  if (wid == 0) {
    float t = 0.0f;
    #pragma unroll
    for (int w = 0; w < 16; ++w) t += ssbuf[w * 64 + lane];
    invs[lane] = (t > 0.0f) ? 1.0f / t : 1.0f;
  }
  __syncthreads();

  {
    const int lr = tid >> 4;
    const int c4 = tid & 15;
    const float s = invs[lr];
    float4 o;
    o.x = ybuf[(4 * c4 + 0) * 65 + lr] * s;
    o.y = ybuf[(4 * c4 + 1) * 65 + lr] * s;
    o.z = ybuf[(4 * c4 + 2) * 65 + lr] * s;
    o.w = ybuf[(4 * c4 + 3) * 65 + lr] * s;
    ((float4*)out)[(size_t)blockIdx.x * 1024 + tid] = o;
  }
}

extern "C" void kernel_launch(void* const* d_in, const int* in_sizes, int n_in,
                              void* d_out, int out_size, void* d_ws, size_t ws_size,
                              hipStream_t stream) {
  const float* inp   = (const float*)d_in[0];
  const float* ident = (const float*)d_in[1];
  const float* enh   = (const float*)d_in[2];
  const float* inh   = (const float*)d_in[3];
  const float* beta  = (const float*)d_in[4];
  const float* delta = (const float*)d_in[5];

  hipLaunchKernelGGL(front_k, dim3(NBLK), dim3(1024), 0, stream,
                     ident, enh, inh, beta, delta, d_ws);
  hipLaunchKernelGGL(batch_k, dim3(256), dim3(1024), 0, stream,
                     inp, (const float*)d_ws, (float*)d_out);
}